// Round 7
// baseline (114.037 us; speedup 1.0000x reference)
//
#include <hip/hip_runtime.h>
#include <math.h>

#define B_ 4
#define C_ 64
#define D_ 32
#define H_ 64
#define W_ 64
#define S_ (D_*H_*W_)      // 131072 spatial per (b,c)
#define S4_ (S_/4)         // 32768

typedef float floatx4 __attribute__((ext_vector_type(4)));

// ---------------- Kernel 1: channel-wise max & mean -> xc[B][2][D][H][W] ----
__global__ __launch_bounds__(256) void reduce_kernel(const float* __restrict__ x,
                                                     float* __restrict__ xc) {
    int i  = blockIdx.x * 256 + threadIdx.x;          // float4 index over B*S/4
    int b  = i >> 15;                                  // i / S4_
    int s4 = i & (S4_ - 1);
    const float4* x4 = reinterpret_cast<const float4*>(x) + (size_t)b * C_ * S4_ + s4;
    float4 v = x4[0];
    float mx0 = v.x, mx1 = v.y, mx2 = v.z, mx3 = v.w;
    float sm0 = v.x, sm1 = v.y, sm2 = v.z, sm3 = v.w;
    #pragma unroll 8
    for (int c = 1; c < C_; ++c) {
        float4 t = x4[(size_t)c * S4_];
        mx0 = fmaxf(mx0, t.x); sm0 += t.x;
        mx1 = fmaxf(mx1, t.y); sm1 += t.y;
        mx2 = fmaxf(mx2, t.z); sm2 += t.z;
        mx3 = fmaxf(mx3, t.w); sm3 += t.w;
    }
    float4* o = reinterpret_cast<float4*>(xc);
    float4 a; a.x = mx0; a.y = mx1; a.z = mx2; a.w = mx3;
    o[((size_t)b * 2 + 0) * S4_ + s4] = a;
    const float inv = 1.0f / 64.0f;
    float4 m; m.x = sm0 * inv; m.y = sm1 * inv; m.z = sm2 * inv; m.w = sm3 * inv;
    o[((size_t)b * 2 + 1) * S4_ + s4] = m;
}

// ---------- Kernel 2: conv3d(2->1,k7,p3) + sigmoid -> scale[B][D][H][W] -----
// Tile: 64(W, full rows) x 4(H) x 4(D) per 256-thread block -> 512 blocks.
// Halo: both channels resident, 2 x 10(z) x 10(y) x 70(x), row stride 72.
#define YS 72
#define ZS (10*YS)         // 720
#define CHS (10*ZS)        // 7200 floats per channel
__global__ __launch_bounds__(256) void conv_kernel(const float* __restrict__ xc,
                                                   const float* __restrict__ cw,
                                                   const float* __restrict__ cb,
                                                   float* __restrict__ scale) {
    __shared__ float tile[2 * CHS];     // 14400 floats = 57.6 KB
    __shared__ float wl[784];           // both channels, 8-padded rows

    const int tid = threadIdx.x;
    const int b  = blockIdx.z >> 3;
    const int d0 = (blockIdx.z & 7) * 4;
    const int h0 = blockIdx.y * 4;

    const int w4 = tid & 15;           // w = 4*w4
    const int hh = (tid >> 4) & 3;     // h = h0 + hh
    const int dd = tid >> 6;           // d = d0 + dd

    // weights, both channels: wl[ch][kz][ky][8], 8th lane zero
    for (int idx = tid; idx < 784; idx += 256) {
        int ch = idx / 392;
        int r  = idx - ch * 392;
        int kz = r / 56;
        int r2 = r - kz * 56;
        int ky = r2 >> 3;
        int kw = r2 & 7;
        wl[idx] = (kw < 7) ? cw[ch * 343 + kz * 49 + ky * 7 + kw] : 0.f;
    }
    // halo, both channels: logical 2 x 10 x 10 x 70
    for (int idx = tid; idx < 2 * 10 * 10 * 70; idx += 256) {
        int ch = idx / 7000;
        int r  = idx - ch * 7000;
        int z  = r / 700;
        int r2 = r - z * 700;
        int y  = r2 / 70;
        int xw = r2 - y * 70;
        int gd = d0 + z - 3, gh = h0 + y - 3, gw = xw - 3;
        float v = 0.f;
        if ((unsigned)gd < (unsigned)D_ && (unsigned)gh < (unsigned)H_ &&
            (unsigned)gw < (unsigned)W_)
            v = xc[((size_t)(b * 2 + ch)) * S_ + gd * (H_ * W_) + gh * W_ + gw];
        tile[ch * CHS + z * ZS + y * YS + xw] = v;
    }
    __syncthreads();

    float acc0 = 0.f, acc1 = 0.f, acc2 = 0.f, acc3 = 0.f;
    for (int ch = 0; ch < 2; ++ch) {
        for (int kz = 0; kz < 7; ++kz) {
            const float* base = &tile[ch * CHS + (dd + kz) * ZS + hh * YS + w4 * 4];
            #pragma unroll
            for (int ky = 0; ky < 7; ++ky) {
                float4 f0 = *reinterpret_cast<const float4*>(base + ky * YS);
                float4 f1 = *reinterpret_cast<const float4*>(base + ky * YS + 4);
                float2 f2 = *reinterpret_cast<const float2*>(base + ky * YS + 8);
                float win[10] = {f0.x, f0.y, f0.z, f0.w, f1.x, f1.y, f1.z, f1.w, f2.x, f2.y};
                const float* wr = &wl[ch * 392 + kz * 56 + ky * 8];
                float4 wa = *reinterpret_cast<const float4*>(wr);
                float4 wb = *reinterpret_cast<const float4*>(wr + 4);
                float wt[7] = {wa.x, wa.y, wa.z, wa.w, wb.x, wb.y, wb.z};
                #pragma unroll
                for (int kw = 0; kw < 7; ++kw) {
                    acc0 = fmaf(win[kw + 0], wt[kw], acc0);
                    acc1 = fmaf(win[kw + 1], wt[kw], acc1);
                    acc2 = fmaf(win[kw + 2], wt[kw], acc2);
                    acc3 = fmaf(win[kw + 3], wt[kw], acc3);
                }
            }
        }
    }

    const float bias = cb[0];
    floatx4 s0;
    s0.x = 1.0f / (1.0f + __expf(-(acc0 + bias)));
    s0.y = 1.0f / (1.0f + __expf(-(acc1 + bias)));
    s0.z = 1.0f / (1.0f + __expf(-(acc2 + bias)));
    s0.w = 1.0f / (1.0f + __expf(-(acc3 + bias)));

    const int d = d0 + dd, h = h0 + hh, w = w4 * 4;
    *reinterpret_cast<floatx4*>(
        &scale[(size_t)b * S_ + (size_t)d * (H_ * W_) + (size_t)h * W_ + w]) = s0;
}

// ---------------- Kernel 3: out = x * scale (broadcast over C) --------------
#define GATE_BLOCKS 2048
__global__ __launch_bounds__(256) void gate_kernel(const float* __restrict__ x,
                                                   const float* __restrict__ scale,
                                                   float* __restrict__ out) {
    const size_t total = (size_t)B_ * C_ * S4_;        // 8388608 float4s
    const size_t stride = (size_t)GATE_BLOCKS * 256;
    for (size_t i = (size_t)blockIdx.x * 256 + threadIdx.x; i < total; i += stride) {
        int b  = (int)(i >> 21);                       // / (C_*S4_)
        int s4 = (int)(i & (S4_ - 1));
        floatx4 xv = reinterpret_cast<const floatx4*>(x)[i];
        floatx4 sv = reinterpret_cast<const floatx4*>(scale)[(size_t)b * S4_ + s4];
        __builtin_nontemporal_store(xv * sv, reinterpret_cast<floatx4*>(out) + i);
    }
}

extern "C" void kernel_launch(void* const* d_in, const int* in_sizes, int n_in,
                              void* d_out, int out_size, void* d_ws, size_t ws_size,
                              hipStream_t stream) {
    const float* x  = (const float*)d_in[0];
    const float* cw = (const float*)d_in[1];   // [1][2][7][7][7]
    const float* cb = (const float*)d_in[2];   // [1]
    float* out   = (float*)d_out;
    float* xc    = (float*)d_ws;                       // B*2*S floats (4 MiB)
    float* scale = xc + (size_t)B_ * 2 * S_;           // B*S floats (2 MiB)

    reduce_kernel<<<dim3((B_ * S4_) / 256), dim3(256), 0, stream>>>(x, xc);
    conv_kernel<<<dim3(1, H_ / 4, B_ * (D_ / 4)), dim3(256), 0, stream>>>(xc, cw, cb, scale);
    gate_kernel<<<dim3(GATE_BLOCKS), dim3(256), 0, stream>>>(x, scale, out);
}

// Round 8
// 102.455 us; speedup vs baseline: 1.1130x; 1.1130x over previous
//
#include <hip/hip_runtime.h>
#include <math.h>

#define B_ 4
#define C_ 64
#define D_ 32
#define H_ 64
#define W_ 64
#define S_ (D_*H_*W_)      // 131072 spatial per (b,c)
#define S4_ (S_/4)         // 32768

typedef float floatx4 __attribute__((ext_vector_type(4)));

// ---------------- Kernel 1: channel-wise max & mean -> xc[B][2][D][H][W] ----
__global__ __launch_bounds__(256) void reduce_kernel(const float* __restrict__ x,
                                                     float* __restrict__ xc) {
    int i  = blockIdx.x * 256 + threadIdx.x;          // float4 index over B*S/4
    int b  = i >> 15;                                  // i / S4_
    int s4 = i & (S4_ - 1);
    const float4* x4 = reinterpret_cast<const float4*>(x) + (size_t)b * C_ * S4_ + s4;
    float4 v = x4[0];
    float mx0 = v.x, mx1 = v.y, mx2 = v.z, mx3 = v.w;
    float sm0 = v.x, sm1 = v.y, sm2 = v.z, sm3 = v.w;
    #pragma unroll 8
    for (int c = 1; c < C_; ++c) {
        float4 t = x4[(size_t)c * S4_];
        mx0 = fmaxf(mx0, t.x); sm0 += t.x;
        mx1 = fmaxf(mx1, t.y); sm1 += t.y;
        mx2 = fmaxf(mx2, t.z); sm2 += t.z;
        mx3 = fmaxf(mx3, t.w); sm3 += t.w;
    }
    float4* o = reinterpret_cast<float4*>(xc);
    float4 a; a.x = mx0; a.y = mx1; a.z = mx2; a.w = mx3;
    o[((size_t)b * 2 + 0) * S4_ + s4] = a;
    const float inv = 1.0f / 64.0f;
    float4 m; m.x = sm0 * inv; m.y = sm1 * inv; m.z = sm2 * inv; m.w = sm3 * inv;
    o[((size_t)b * 2 + 1) * S4_ + s4] = m;
}

// ------- Kernel 2 (fused): conv3d(2->1,k7,p3) + sigmoid + out = x*scale -----
// Tile: 64(W full rows) x 4(H) x 2(D) per 128-thread block -> 1024 blocks
// (~4 generations/CU, ~5 resident by LDS). Staggered retirement pipelines
// gen k's HBM-bound gating under gen k+1's LDS/VALU-bound conv.
// Halo one channel at a time: 8(z) x 10(y) x 70(x), row stride 72 (16B-aligned
// b128 reads, uniform 8 word-accesses/bank per wave).
#define HYS 72
#define HZS (10*HYS)       // 720: z-plane stride
__global__ __launch_bounds__(128) void conv_gate_kernel(const float* __restrict__ xc,
                                                        const float* __restrict__ x,
                                                        const float* __restrict__ cw,
                                                        const float* __restrict__ cb,
                                                        float* __restrict__ out) {
    __shared__ float tile[8 * HZS];     // 5760 floats = 23 KB
    __shared__ float wl[784];           // both channels' weights, 8-padded rows

    const int tid = threadIdx.x;
    const int b  = blockIdx.z >> 4;            // 16 d-slabs per batch
    const int d0 = (blockIdx.z & 15) * 2;
    const int h0 = blockIdx.y * 4;

    const int w4 = tid & 15;           // w = 4*w4 (16 lanes cover a full W-row)
    const int hh = (tid >> 4) & 3;     // h = h0 + hh
    const int dd = tid >> 6;           // d = d0 + dd (0..1)

    // weights, both channels: wl[ch][kz][ky][8], 8th lane zero
    for (int idx = tid; idx < 784; idx += 128) {
        int ch = idx / 392;
        int r  = idx - ch * 392;
        int kz = r / 56;
        int r2 = r - kz * 56;
        int ky = r2 >> 3;
        int kw = r2 & 7;
        wl[idx] = (kw < 7) ? cw[ch * 343 + kz * 49 + ky * 7 + kw] : 0.f;
    }

    float acc0 = 0.f, acc1 = 0.f, acc2 = 0.f, acc3 = 0.f;
    for (int ch = 0; ch < 2; ++ch) {
        // halo for this channel: logical 8 x 10 x 70
        for (int idx = tid; idx < 8 * 10 * 70; idx += 128) {
            int z  = idx / 700;
            int r2 = idx - z * 700;
            int y  = r2 / 70;
            int xw = r2 - y * 70;
            int gd = d0 + z - 3, gh = h0 + y - 3, gw = xw - 3;
            float v = 0.f;
            if ((unsigned)gd < (unsigned)D_ && (unsigned)gh < (unsigned)H_ &&
                (unsigned)gw < (unsigned)W_)
                v = xc[((size_t)(b * 2 + ch)) * S_ + gd * (H_ * W_) + gh * W_ + gw];
            tile[z * HZS + y * HYS + xw] = v;
        }
        __syncthreads();

        for (int kz = 0; kz < 7; ++kz) {
            const float* base = &tile[(dd + kz) * HZS + hh * HYS + w4 * 4];
            const float* wch  = &wl[ch * 392 + kz * 56];
            #pragma unroll
            for (int ky = 0; ky < 7; ++ky) {
                float4 f0 = *reinterpret_cast<const float4*>(base + ky * HYS);
                float4 f1 = *reinterpret_cast<const float4*>(base + ky * HYS + 4);
                float2 f2 = *reinterpret_cast<const float2*>(base + ky * HYS + 8);
                float win[10] = {f0.x, f0.y, f0.z, f0.w, f1.x, f1.y, f1.z, f1.w, f2.x, f2.y};
                float4 wa = *reinterpret_cast<const float4*>(wch + ky * 8);
                float4 wb = *reinterpret_cast<const float4*>(wch + ky * 8 + 4);
                float wt[7] = {wa.x, wa.y, wa.z, wa.w, wb.x, wb.y, wb.z};
                #pragma unroll
                for (int kw = 0; kw < 7; ++kw) {
                    acc0 = fmaf(win[kw + 0], wt[kw], acc0);
                    acc1 = fmaf(win[kw + 1], wt[kw], acc1);
                    acc2 = fmaf(win[kw + 2], wt[kw], acc2);
                    acc3 = fmaf(win[kw + 3], wt[kw], acc3);
                }
            }
        }
        __syncthreads();   // before next channel's fill overwrites the tile
    }

    // ---- sigmoid in registers ----
    const float bias = cb[0];
    floatx4 s0;
    s0.x = 1.0f / (1.0f + __expf(-(acc0 + bias)));
    s0.y = 1.0f / (1.0f + __expf(-(acc1 + bias)));
    s0.z = 1.0f / (1.0f + __expf(-(acc2 + bias)));
    s0.w = 1.0f / (1.0f + __expf(-(acc3 + bias)));

    // ---- apply gate to all 64 channels at this thread's float4 ----
    // wave (64 lanes) = 4 adjacent H-rows x full W = one contiguous 1KB span
    const int d = d0 + dd, h = h0 + hh, w = w4 * 4;
    const size_t sp = (size_t)d * (H_ * W_) + (size_t)h * W_ + w;
    const float* xp = x + (size_t)b * C_ * S_ + sp;
    float* op = out + (size_t)b * C_ * S_ + sp;
    #pragma unroll 8
    for (int c = 0; c < C_; ++c) {
        const size_t off = (size_t)c * S_;
        floatx4 xv = *reinterpret_cast<const floatx4*>(xp + off);
        *reinterpret_cast<floatx4*>(op + off) = xv * s0;
    }
}

extern "C" void kernel_launch(void* const* d_in, const int* in_sizes, int n_in,
                              void* d_out, int out_size, void* d_ws, size_t ws_size,
                              hipStream_t stream) {
    const float* x  = (const float*)d_in[0];
    const float* cw = (const float*)d_in[1];   // [1][2][7][7][7]
    const float* cb = (const float*)d_in[2];   // [1]
    float* out = (float*)d_out;
    float* xc  = (float*)d_ws;                 // B*2*S floats (4 MiB)

    reduce_kernel<<<dim3((B_ * S4_) / 256), dim3(256), 0, stream>>>(x, xc);
    conv_gate_kernel<<<dim3(1, H_ / 4, B_ * (D_ / 2)), dim3(128), 0, stream>>>(
        xc, x, cw, cb, out);
}